// Round 1
// baseline (1126.548 us; speedup 1.0000x reference)
//
#include <hip/hip_runtime.h>
#include <hip/hip_bf16.h>

// ---------------------------------------------------------------------------
// RGCN (basis decomposition) x4 layers + pair-scoring head.
// Strategy:
//   - Build CSR by dst once per call (histogram -> scan -> fill), pack
//     (src, etype) into one u32 per edge.
//   - Per layer: k_transform computes hb[n,b,:] = x@basis[b] and the self
//     part (x@wself + bias) written directly into the cat buffer; then
//     k_aggregate pulls over in-edges (no atomics) and applies tanh in place.
//   - cat buffer [N,128] f32 holds all four layer states (concat layout),
//     so layer l reads cols (l-1)*32.. and writes cols l*32...
//   - Head: one wave per pair, 256-dim dot + sigmoid.
// ---------------------------------------------------------------------------

#define ETYPE_SHIFT 28
#define SRC_MASK 0x0FFFFFFFu

__global__ void k_count(const int* __restrict__ dst, int* __restrict__ deg, int E) {
    int e = blockIdx.x * 256 + threadIdx.x;
    if (e < E) atomicAdd(&deg[dst[e]], 1);
}

// Block-level inclusive scan of deg (256 elems/block); writes rowptr[i+1]
// (un-offset) and per-block totals.
__global__ void k_scan_block(const int* __restrict__ deg, int* __restrict__ rowptr,
                             int* __restrict__ blockSums, int n) {
    int i = blockIdx.x * 256 + threadIdx.x;
    int v = (i < n) ? deg[i] : 0;
    int val = v;
    int lane = threadIdx.x & 63;
    int wid = threadIdx.x >> 6;
    for (int d = 1; d < 64; d <<= 1) {
        int t = __shfl_up(val, d, 64);
        if (lane >= d) val += t;
    }
    __shared__ int wsum[4];
    if (lane == 63) wsum[wid] = val;
    __syncthreads();
    int off = 0;
    for (int w = 0; w < wid; ++w) off += wsum[w];
    val += off;
    if (i < n) rowptr[i + 1] = val;
    if (threadIdx.x == 255) blockSums[blockIdx.x] = val;
}

// Single-block Hillis-Steele scan of block sums (nb <= 1024).
__global__ void k_scan_sums(const int* __restrict__ blockSums,
                            int* __restrict__ blockOffsets, int nb) {
    __shared__ int lds[1024];
    int tid = threadIdx.x;
    int v = (tid < nb) ? blockSums[tid] : 0;
    lds[tid] = v;
    __syncthreads();
    for (int d = 1; d < 1024; d <<= 1) {
        int t = (tid >= d) ? lds[tid - d] : 0;
        __syncthreads();
        lds[tid] += t;
        __syncthreads();
    }
    if (tid < nb) blockOffsets[tid] = lds[tid] - v;  // exclusive
}

__global__ void k_scan_add(int* __restrict__ rowptr, int* __restrict__ cursor,
                           const int* __restrict__ blockOffsets, int n) {
    int i = blockIdx.x * 256 + threadIdx.x;
    if (i == 0) { rowptr[0] = 0; cursor[0] = 0; }
    if (i < n) {
        int v = rowptr[i + 1] + blockOffsets[blockIdx.x];
        rowptr[i + 1] = v;
        cursor[i + 1] = v;
    }
}

__global__ void k_fill(const int* __restrict__ src, const int* __restrict__ dst,
                       const int* __restrict__ etype, int* __restrict__ cursor,
                       unsigned int* __restrict__ epack, int E) {
    int e = blockIdx.x * 256 + threadIdx.x;
    if (e < E) {
        int d = dst[e];
        int pos = atomicAdd(&cursor[d], 1);
        epack[pos] = (unsigned int)src[e] | ((unsigned int)etype[e] << ETYPE_SHIFT);
    }
}

// hb[n,b,o] = sum_i x[n,i]*basis[b,i,o];  selfout[n,o] = sum_i x[n,i]*wself[i,o] + bias[o]
// One thread per (node, o). 8 nodes per 256-thread block.
__global__ void k_transform(const float* __restrict__ xin, int in_stride, int di,
                            const float* __restrict__ basis,
                            const float* __restrict__ wself,
                            const float* __restrict__ bias,
                            float* __restrict__ hb,
                            float* __restrict__ selfout,  // cat + l*32, row stride 128
                            int n) {
    int t = blockIdx.x * 256 + threadIdx.x;
    int node = t >> 5;
    int o = t & 31;
    if (node >= n) return;
    const float* xr = xin + (size_t)node * in_stride;
    const float* b0 = basis + o;
    const float* b1 = basis + (size_t)di * 32 + o;
    const float* ws = wself + o;
    float a0 = 0.f, a1 = 0.f, as = 0.f;
    for (int i = 0; i < di; ++i) {
        float xv = xr[i];
        a0 = fmaf(xv, b0[i * 32], a0);
        a1 = fmaf(xv, b1[i * 32], a1);
        as = fmaf(xv, ws[i * 32], as);
    }
    hb[(size_t)node * 64 + o] = a0;
    hb[(size_t)node * 64 + 32 + o] = a1;
    selfout[(size_t)node * 128 + o] = as + bias[o];
}

// Pull aggregation + tanh, in place on cat columns.
__global__ void k_aggregate(const float* __restrict__ hb,
                            const unsigned int* __restrict__ epack,
                            const int* __restrict__ rowptr,
                            const float* __restrict__ comp,  // [8,2]
                            float* __restrict__ cat_l,       // cat + l*32, stride 128
                            int n) {
    __shared__ float c[16];
    if (threadIdx.x < 16) c[threadIdx.x] = comp[threadIdx.x];
    __syncthreads();
    int t = blockIdx.x * 256 + threadIdx.x;
    int node = t >> 5;
    int o = t & 31;
    if (node >= n) return;
    float acc = cat_l[(size_t)node * 128 + o];
    int k0 = rowptr[node], k1 = rowptr[node + 1];
    for (int k = k0; k < k1; ++k) {
        unsigned int p = epack[k];
        int s = (int)(p & SRC_MASK);
        int et = (int)(p >> ETYPE_SHIFT);
        acc = fmaf(c[et * 2 + 0], hb[(size_t)s * 64 + o], acc);
        acc = fmaf(c[et * 2 + 1], hb[(size_t)s * 64 + 32 + o], acc);
    }
    cat_l[(size_t)node * 128 + o] = tanhf(acc);
}

// One wave per pair: 256-dim dot + sigmoid.
__global__ void k_head(const float* __restrict__ cat, const int* __restrict__ uidx,
                       const int* __restrict__ iidx, const float* __restrict__ w,
                       const float* __restrict__ b, float* __restrict__ out, int B) {
    int p = blockIdx.x;
    if (p >= B) return;
    int lane = threadIdx.x;  // 0..63
    const float* cu = cat + (size_t)uidx[p] * 128;
    const float* ci = cat + (size_t)iidx[p] * 128;
    float s = 0.f;
    s = fmaf(cu[lane], w[lane], s);
    s = fmaf(cu[lane + 64], w[lane + 64], s);
    s = fmaf(ci[lane], w[lane + 128], s);
    s = fmaf(ci[lane + 64], w[lane + 192], s);
    for (int d = 32; d > 0; d >>= 1) s += __shfl_down(s, d, 64);
    if (lane == 0) out[p] = 1.f / (1.f + expf(-(s + b[0])));
}

extern "C" void kernel_launch(void* const* d_in, const int* in_sizes, int n_in,
                              void* d_out, int out_size, void* d_ws, size_t ws_size,
                              hipStream_t stream) {
    const float* x      = (const float*)d_in[0];
    const int*   src    = (const int*)d_in[1];
    const int*   dst    = (const int*)d_in[2];
    const int*   etype  = (const int*)d_in[3];
    const int*   uidx   = (const int*)d_in[4];
    const int*   iidx   = (const int*)d_in[5];
    const float* lin1_w = (const float*)d_in[22];
    const float* lin1_b = (const float*)d_in[23];

    const int N = in_sizes[0] / 64;
    const int E = in_sizes[1];
    const int B = in_sizes[4];

    // workspace carve-out (256B aligned)
    char* p = (char*)d_ws;
    auto alloc = [&](size_t bytes) -> void* {
        void* r = (void*)p;
        p += (bytes + 255) & ~(size_t)255;
        return r;
    };
    float*        hb           = (float*)alloc((size_t)N * 64 * sizeof(float));
    float*        cat          = (float*)alloc((size_t)N * 128 * sizeof(float));
    int*          rowptr       = (int*)alloc((size_t)(N + 1) * sizeof(int));
    int*          cursor       = (int*)alloc((size_t)(N + 1) * sizeof(int));
    unsigned int* epack        = (unsigned int*)alloc((size_t)E * sizeof(unsigned int));
    int           nb           = (N + 255) / 256;
    int*          blockSums    = (int*)alloc((size_t)nb * sizeof(int));
    int*          blockOffsets = (int*)alloc((size_t)nb * sizeof(int));

    // ---- CSR build (per call; deterministic work) ----
    hipMemsetAsync(cursor, 0, (size_t)(N + 1) * sizeof(int), stream);
    k_count<<<(E + 255) / 256, 256, 0, stream>>>(dst, cursor, E);
    k_scan_block<<<nb, 256, 0, stream>>>(cursor, rowptr, blockSums, N);
    k_scan_sums<<<1, 1024, 0, stream>>>(blockSums, blockOffsets, nb);
    k_scan_add<<<nb, 256, 0, stream>>>(rowptr, cursor, blockOffsets, N);
    k_fill<<<(E + 255) / 256, 256, 0, stream>>>(src, dst, etype, cursor, epack, E);

    // ---- 4 RGCN layers ----
    int node_grid = (N * 32 + 255) / 256;
    for (int l = 0; l < 4; ++l) {
        const float* xin   = (l == 0) ? x : (cat + (size_t)(l - 1) * 32);
        int in_stride      = (l == 0) ? 64 : 128;
        int di             = (l == 0) ? 64 : 32;
        const float* basis = (const float*)d_in[6 + l * 4];
        const float* comp  = (const float*)d_in[7 + l * 4];
        const float* wself = (const float*)d_in[8 + l * 4];
        const float* bias  = (const float*)d_in[9 + l * 4];
        k_transform<<<node_grid, 256, 0, stream>>>(xin, in_stride, di, basis, wself,
                                                   bias, hb, cat + (size_t)l * 32, N);
        k_aggregate<<<node_grid, 256, 0, stream>>>(hb, epack, rowptr, comp,
                                                   cat + (size_t)l * 32, N);
    }

    // ---- head ----
    k_head<<<B, 64, 0, stream>>>(cat, uidx, iidx, lin1_w, lin1_b, (float*)d_out, B);
}